// Round 1
// baseline (233.597 us; speedup 1.0000x reference)
//
#include <hip/hip_runtime.h>

// TELIF: temporal-encoding LIF neuron scan.
// tx: [T, B, N] fp32, TE: [N, T] fp32, out ty: [T, B, N] fp32 (0/1 spikes).
// T=512, B=64, N=1024. One consumer thread per (b,n) sequence, sequential t.
//
// v2: producer/consumer LDS pipeline.
//   Problem size caps occupancy at 1 compute wave/SIMD, and the v1 register
//   double-buffer ended every 16-step chunk with an in-order vmcnt drain of
//   BOTH the prefetch loads and the chunk's nontemporal stores -> latency-
//   serialized rounds at ~1-3 TB/s effective.
//   Now block = 320 threads: 4 consumer waves (recurrence, x from LDS via
//   ds_read -> lgkmcnt only, stores never waited on) + 1 producer wave
//   streaming tx into a 4-slot LDS ring with global_load_lds dwordx4
//   (1 KB/instr). Producer runs 3 chunks ahead with counted
//   s_waitcnt vmcnt(32) + RAW s_barrier (NOT __syncthreads, whose implicit
//   vmcnt(0) drain would collapse the pipeline). 32-48 KB in flight per CU
//   >> bandwidth-delay product -> HBM-bound.

#define T_STEPS 512
#define BATCH   64
#define NNEUR   1024
#define BN      (BATCH * NNEUR)
#define UCHUNK  16
#define NCHUNK  (T_STEPS / UCHUNK)   // 32
#define NSLOT   4                    // LDS ring depth (chunks)
#define CONS_THREADS 256
#define BLOCK_THREADS 320            // 4 consumer waves + 1 producer wave

__global__ __launch_bounds__(BLOCK_THREADS) void telif_kernel(
    const float* __restrict__ tx, const float* __restrict__ TE,
    float* __restrict__ out)
{
    // Reference is validated against fp32 elementwise ops with a hard
    // (v > th) threshold: forbid FMA contraction so rounding matches exactly.
#pragma clang fp contract(off)

    // Ring buffer: slot s holds one 16-step chunk of tx for this block's
    // 256 sequences. 4 * 16 * 256 * 4 B = 64 KiB LDS.
    __shared__ float buf[NSLOT][UCHUNK][CONS_THREADS];

    const int tid = threadIdx.x;
    const int blockBase = blockIdx.x * CONS_THREADS;   // first flat index

    if (tid >= CONS_THREADS) {
        // ---------------- producer wave (threads 256..319) ----------------
        const int lane = tid - CONS_THREADS;           // 0..63
        // Each lane DMAs 16 B: one global_load_lds_dwordx4 per t-row moves
        // the whole 1 KB row (256 floats) into LDS linearly.
        const float* gbase = tx + blockBase + lane * 4;

        auto issue_chunk = [&](int k) {
            const int slot = k & (NSLOT - 1);
#pragma unroll
            for (int u = 0; u < UCHUNK; ++u) {
                const float* g = gbase + (size_t)(k * UCHUNK + u) * BN;
                __builtin_amdgcn_global_load_lds(
                    (const __attribute__((address_space(1))) void*)g,
                    (__attribute__((address_space(3))) void*)&buf[slot][u][0],
                    16, 0, 0);
            }
        };

        // Prologue: chunks 0..2 in flight (48 loads), ensure chunk 0 done.
        issue_chunk(0);
        issue_chunk(1);
        issue_chunk(2);
        asm volatile("s_waitcnt vmcnt(32)" ::: "memory");
        __builtin_amdgcn_sched_barrier(0);
        __builtin_amdgcn_s_barrier();                  // barrier #1: chunk 0 ready

        for (int r = 0; r < NCHUNK; ++r) {
            // Slot (r+3)&3 was released by consumers at the previous barrier.
            if (r + 3 < NCHUNK) issue_chunk(r + 3);
            // Guarantee chunk r+1 complete before the barrier that opens
            // round r+1. Outstanding newest loads: chunks r+2, r+3.
            if (r <= NCHUNK - 4) {
                asm volatile("s_waitcnt vmcnt(32)" ::: "memory");
            } else if (r == NCHUNK - 3) {
                asm volatile("s_waitcnt vmcnt(16)" ::: "memory");
            } else {
                asm volatile("s_waitcnt vmcnt(0)" ::: "memory");
            }
            __builtin_amdgcn_sched_barrier(0);
            __builtin_amdgcn_s_barrier();              // barriers #2..#33
        }
        return;
    }

    // ---------------- consumer waves (threads 0..255) ----------------
    const int flat = blockBase + tid;                  // b*N + n
    const int n = flat & (NNEUR - 1);
    const float* tep = TE + n * T_STEPS;               // contiguous along t
    float*       outp = out + flat;

    float v  = 0.0f;   // REST
    float y  = 0.0f;
    float th = 0.3f;   // THRESHOLD

    // TE double-buffer in registers (L1-resident loads, one chunk ahead).
    float tc[UCHUNK], tn[UCHUNK];
#pragma unroll
    for (int u = 0; u < UCHUNK; u += 4) {
        float4 f = *reinterpret_cast<const float4*>(tep + u);
        tc[u] = f.x; tc[u + 1] = f.y; tc[u + 2] = f.z; tc[u + 3] = f.w;
    }
    __builtin_amdgcn_s_barrier();                      // barrier #1: chunk 0 ready

#pragma unroll 1
    for (int r = 0; r < NCHUNK; ++r) {
        const int t = r * UCHUNK;

        // Prefetch next chunk's TE into registers.
        if (r + 1 < NCHUNK) {
#pragma unroll
            for (int u = 0; u < UCHUNK; u += 4) {
                float4 f = *reinterpret_cast<const float4*>(tep + t + UCHUNK + u);
                tn[u] = f.x; tn[u + 1] = f.y; tn[u + 2] = f.z; tn[u + 3] = f.w;
            }
        }

        // x from LDS: addr = tid*4 B, stride-1 across lanes -> 2 lanes/bank,
        // conflict-free. lgkmcnt waits only; stores never block the loop.
        const float* xs = &buf[r & (NSLOT - 1)][0][tid];
#pragma unroll
        for (int u = 0; u < UCHUNK; ++u) {
            float x = xs[(size_t)u * CONS_THREADS];
            // Exact op order of the reference:
            //   th = th + v*te - (th - THRESHOLD)*BETA
            //   v  = v*DECAY*(1-y) + x
            //   y  = (v > th)
            float a    = v * tc[u];
            float bsum = th + a;
            float c    = th - 0.3f;
            float d    = c * 0.02f;
            th = bsum - d;
            float e  = v * 0.2f;
            float f1 = 1.0f - y;
            float g  = e * f1;
            v = g + x;
            y = (v > th) ? 1.0f : 0.0f;
            __builtin_nontemporal_store(y, outp + (size_t)(t + u) * BN);
        }

#pragma unroll
        for (int u = 0; u < UCHUNK; ++u) tc[u] = tn[u];

        __builtin_amdgcn_s_barrier();                  // release slot r&3
    }
}

extern "C" void kernel_launch(void* const* d_in, const int* in_sizes, int n_in,
                              void* d_out, int out_size, void* d_ws, size_t ws_size,
                              hipStream_t stream) {
    const float* tx = (const float*)d_in[0];  // [T, B, N]
    const float* TE = (const float*)d_in[1];  // [N, T]
    float* out = (float*)d_out;               // [T, B, N]
    telif_kernel<<<BN / CONS_THREADS, BLOCK_THREADS, 0, stream>>>(tx, TE, out);
}